// Round 4
// baseline (129.328 us; speedup 1.0000x reference)
//
#include <hip/hip_runtime.h>
#include <hip/hip_bf16.h>
#include <math.h>

typedef __attribute__((ext_vector_type(8))) short short8;
typedef __attribute__((ext_vector_type(4))) float f32x4;
typedef __attribute__((ext_vector_type(4))) unsigned int uint4v;

// Problem constants (B=8, S=4096, F=768, N=128)
constexpr int kF = 768;
constexpr int kN = 128;
constexpr int kB = 8;
constexpr int kS = 4096;
constexpr int kM = kB * kS;          // 32768 rows

// Workspace layout (BYTE offsets), ~34.6 MB total (round 1-3 used ~36-37 MB OK)
// [0, 4096)           scalars f32: [0]Ar [128]Ai [256]P1r(A^32) [384]P1i
//                     [512]coef_r [640]coef_i [768]P4r(A^128) [896]P4i
// [4096, +393216)     Bw [256][768] bf16 : row c (c<128 Re, else Im of coef*B)
// [397312, +393216)   Cw [768][256] bf16 : row f, k<128 = C_re[f][k], else -C_im
// [790528, +262144)   finals [8][32][256] f32 (re at n, im at 128+n)
// [1052672, +1024)    flags [256] u32
// [1053696, +33554432) x [32768][256] f32
constexpr size_t kOffBw     = 4096;
constexpr size_t kOffCw     = 397312;
constexpr size_t kOffFinals = 790528;
constexpr size_t kOffFlags  = 1052672;
constexpr size_t kOffX      = 1053696;

__device__ __forceinline__ unsigned short f2bf(float f) {
    unsigned int u = __builtin_bit_cast(unsigned int, f);
    u += 0x7fffu + ((u >> 16) & 1u);   // round-to-nearest-even
    return (unsigned short)(u >> 16);
}

#define LGKM0_BAR() do { \
    asm volatile("s_waitcnt lgkmcnt(0)" ::: "memory"); \
    __builtin_amdgcn_s_barrier(); \
    __builtin_amdgcn_sched_barrier(0); \
} while (0)

__global__ __launch_bounds__(128)
void pre1(const float* __restrict__ log_A_real, const float* __restrict__ A_imag,
          const float* __restrict__ log_dt, float* __restrict__ ws) {
    int n = threadIdx.x;
    float dt = expf(log_dt[n]);
    float ar = -expf(log_A_real[n]);
    float ai = A_imag[n];
    float er = expf(ar * dt);
    float Ar = er * cosf(ai * dt);
    float Ai = er * sinf(ai * dt);
    // coef = (A_bar - 1) / (A_diag + 1e-8)
    float dr = ar + 1e-8f, di = ai;
    float inv = 1.0f / (dr * dr + di * di);
    float nr = Ar - 1.0f, ni = Ai;
    float cr = (nr * dr + ni * di) * inv;
    float ci = (ni * dr - nr * di) * inv;
    // P1 = A^32 by repeated multiply
    float pr = 1.f, pi = 0.f;
    for (int i = 0; i < 32; ++i) {
        float t = pr * Ar - pi * Ai;
        pi = pr * Ai + pi * Ar;
        pr = t;
    }
    // P4 = A^128 = (P1^2)^2
    float sr = pr * pr - pi * pi, si = 2.f * pr * pi;
    float qr = sr * sr - si * si, qi = 2.f * sr * si;
    ws[n] = Ar;        ws[128 + n] = Ai;
    ws[256 + n] = pr;  ws[384 + n] = pi;
    ws[512 + n] = cr;  ws[640 + n] = ci;
    ws[768 + n] = qr;  ws[896 + n] = qi;
}

__global__ __launch_bounds__(256)
void pre2(const float* __restrict__ B_re, const float* __restrict__ B_im,
          const float* __restrict__ wsf, unsigned short* __restrict__ bw) {
    int id = blockIdx.x * 256 + threadIdx.x;   // 0 .. 256*768-1
    int c = id / kF;
    int f = id - c * kF;
    int n = c & 127;
    float cr = wsf[512 + n], ci = wsf[640 + n];
    float br = B_re[n * kF + f], bi = B_im[n * kF + f];
    float v = (c < 128) ? (cr * br - ci * bi) : (cr * bi + ci * br);
    bw[id] = f2bf(v);
}

__global__ __launch_bounds__(256)
void pre3(const float* __restrict__ C_re, const float* __restrict__ C_im,
          unsigned short* __restrict__ cw) {
    int id = blockIdx.x * 256 + threadIdx.x;   // 0 .. 768*256-1
    int f = id >> 8;
    int k = id & 255;
    float v = (k < 128) ? C_re[f * kN + k] : -C_im[f * kN + (k - 128)];
    cw[id] = f2bf(v);
}

// Fused: Bu-tile GEMM (128 rows x 256 cols, K=768) -> in-LDS chunk scan ->
// decoupled lookback over predecessor blocks (same batch) -> write final x.
// 256 blocks x 512 threads; 141 KB LDS => exactly 1 block/CU, all co-resident.
__global__ __launch_bounds__(512, 2)
void gemm1_scan(const float* __restrict__ A,          // u [32768][768]
                const unsigned short* __restrict__ W, // Bw [256][768]
                float* __restrict__ xout,             // [32768][256]
                float* __restrict__ finals,           // [8][32][256]
                unsigned int* __restrict__ flags,     // [256]
                const float* __restrict__ wsf) {
    constexpr int K  = kF;      // 768
    constexpr int KT = K / 32;  // 24
    __shared__ __align__(16) char smem[141312];
    short* As0 = (short*)smem;            // [128*40] bf16
    short* As1 = As0 + 128 * 40;
    short* Ws0 = As1 + 128 * 40;          // [256*40] bf16
    short* Ws1 = Ws0 + 256 * 40;
    float* xbuf = (float*)smem;           // [128][260] f32 (reuses tile space)
    float* gbuf = (float*)(smem + 133120);// [4][2][128] chunk finals G_q
    float* sbuf = (float*)(smem + 137216);// [4][2][128] chunk seeds

    const int blk = blockIdx.x;           // 0..255 (row-block, s-ordered)
    const int m0  = blk * 128;
    const int b   = blk >> 5;             // batch
    const int ci  = blk & 31;             // chunk-block index within batch

    const int t = threadIdx.x;
    const int arow = t >> 2, aq = t & 3;   // A staging: 8 floats
    const int wrow = t >> 1, wh = t & 1;   // W staging: 16 bf16

    const int wave = t >> 6, lane = t & 63;
    const int wm = wave >> 2, wn = wave & 3;     // 2 x 4 wave grid (64x64 tiles)
    const int lr = lane & 15, lg = lane >> 4;

    f32x4 acc[4][4] = {};

    f32x4 aA0, aA1, aB0, aB1;
    uint4v wA0, wA1, wB0, wB1;
    const float* aptr = A + (size_t)(m0 + arow) * K + aq * 8;
    const unsigned short* wptr = W + (size_t)wrow * K + wh * 16;

#define G1_LOAD(SET, kt) do { \
    const float* p_ = aptr + (kt) * 32; \
    a##SET##0 = *(const f32x4*)p_; a##SET##1 = *(const f32x4*)(p_ + 4); \
    const unsigned short* q_ = wptr + (kt) * 32; \
    w##SET##0 = *(const uint4v*)q_; w##SET##1 = *(const uint4v*)(q_ + 8); \
} while (0)

#define G1_WRITE(Asb, Wsb, a0, a1, w0, w1) do { \
    short h_[8]; \
    _Pragma("unroll") for (int e_ = 0; e_ < 4; ++e_) { \
        h_[e_]     = (short)f2bf(a0[e_]); \
        h_[4 + e_] = (short)f2bf(a1[e_]); \
    } \
    *(short8*)(&Asb[arow * 40 + aq * 8]) = *(short8*)h_; \
    *(short8*)(&Wsb[wrow * 40 + wh * 16])     = *(short8*)&w0; \
    *(short8*)(&Wsb[wrow * 40 + wh * 16 + 8]) = *(short8*)&w1; \
} while (0)

#define G1_MMA(Asb, Wsb) do { \
    short8 ah_[4], bh_[4]; \
    _Pragma("unroll") for (int i_ = 0; i_ < 4; ++i_) { \
        ah_[i_] = *(const short8*)(&Asb[(wm * 64 + i_ * 16 + lr) * 40 + lg * 8]); \
        bh_[i_] = *(const short8*)(&Wsb[(wn * 64 + i_ * 16 + lr) * 40 + lg * 8]); \
    } \
    _Pragma("unroll") for (int i_ = 0; i_ < 4; ++i_) \
    _Pragma("unroll") for (int j_ = 0; j_ < 4; ++j_) \
        acc[i_][j_] = __builtin_amdgcn_mfma_f32_16x16x32_bf16(ah_[i_], bh_[j_], acc[i_][j_], 0, 0, 0); \
} while (0)

    G1_LOAD(A, 0);
    G1_LOAD(B, 1);
    for (int kt = 0; kt < KT; kt += 2) {
        G1_WRITE(As0, Ws0, aA0, aA1, wA0, wA1);
        if (kt + 2 < KT) G1_LOAD(A, kt + 2);
        LGKM0_BAR();
        G1_MMA(As0, Ws0);
        G1_WRITE(As1, Ws1, aB0, aB1, wB0, wB1);
        if (kt + 3 < KT) G1_LOAD(B, kt + 3);
        LGKM0_BAR();
        G1_MMA(As1, Ws1);
    }

    // ---- dump acc (Bu values) into LDS x-buffer [128][260] ----
    __syncthreads();
#pragma unroll
    for (int i = 0; i < 4; ++i)
#pragma unroll
        for (int j = 0; j < 4; ++j) {
            const int col = wn * 64 + j * 16 + lr;
#pragma unroll
            for (int q = 0; q < 4; ++q)
                xbuf[(wm * 64 + i * 16 + lg * 4 + q) * 260 + col] = acc[i][j][q];
        }
    __syncthreads();

    // ---- chunk-local zero-init scans (4 chunks x 128 n), in place ----
    const int sq = t >> 7;     // chunk 0..3
    const int sn = t & 127;    // state index
    const float Ar = wsf[sn], Ai = wsf[128 + sn];
    {
        float xr = 0.f, xi = 0.f;
        const int r0 = sq * 32;
        for (int tt = 0; tt < 32; ++tt) {
            float* pr = &xbuf[(r0 + tt) * 260 + sn];
            float* pim = &xbuf[(r0 + tt) * 260 + 128 + sn];
            float br = *pr, bi = *pim;
            float trr = Ar * xr - Ai * xi + br;
            xi = Ar * xi + Ai * xr + bi;
            xr = trr;
            *pr = xr; *pim = xi;
        }
        gbuf[(sq * 2 + 0) * 128 + sn] = xr;
        gbuf[(sq * 2 + 1) * 128 + sn] = xi;
    }
    __syncthreads();

    // ---- block final F = compose(G0..G3 with P1=A^32), publish ----
    if (t < 128) {
        const float P1r = wsf[256 + sn], P1i = wsf[384 + sn];
        float fr = 0.f, fi = 0.f;
#pragma unroll
        for (int q = 0; q < 4; ++q) {
            float gr = gbuf[(q * 2 + 0) * 128 + sn];
            float gi = gbuf[(q * 2 + 1) * 128 + sn];
            float trr = P1r * fr - P1i * fi + gr;
            fi = P1r * fi + P1i * fr + gi;
            fr = trr;
        }
        finals[(size_t)blk * 256 + sn]       = fr;
        finals[(size_t)blk * 256 + 128 + sn] = fi;
        __threadfence();   // device-scope: finals visible before flag
    }
    __syncthreads();
    if (t == 0)
        __hip_atomic_store(&flags[blk], 1u, __ATOMIC_RELEASE, __HIP_MEMORY_SCOPE_AGENT);

    // ---- lookback: wait for all predecessor blocks in this batch ----
    if (t < ci) {
        const unsigned int* fp = &flags[b * 32 + t];
        while (__hip_atomic_load(fp, __ATOMIC_ACQUIRE, __HIP_MEMORY_SCOPE_AGENT) == 0u)
            __builtin_amdgcn_s_sleep(1);
        __threadfence();
    }
    __syncthreads();

    // ---- compose carry C = sum_j P4^{ci-1-j} F_j ; then chunk seeds ----
    if (t < 128) {
        const float P4r = wsf[768 + sn], P4i = wsf[896 + sn];
        float cr = 0.f, cii = 0.f;
        for (int j = 0; j < ci; ++j) {
            size_t o = (size_t)(b * 32 + j) * 256;
            float fr = finals[o + sn], fi = finals[o + 128 + sn];
            float trr = P4r * cr - P4i * cii + fr;
            cii = P4r * cii + P4i * cr + fi;
            cr = trr;
        }
        const float P1r = wsf[256 + sn], P1i = wsf[384 + sn];
        float sr = cr, si = cii;
#pragma unroll
        for (int q = 0; q < 4; ++q) {
            sbuf[(q * 2 + 0) * 128 + sn] = sr;
            sbuf[(q * 2 + 1) * 128 + sn] = si;
            float gr = gbuf[(q * 2 + 0) * 128 + sn];
            float gi = gbuf[(q * 2 + 1) * 128 + sn];
            float trr = P1r * sr - P1i * si + gr;
            si = P1r * si + P1i * sr + gi;
            sr = trr;
        }
    }
    __syncthreads();

    // ---- correction: x[t] += A^{t+1} * seed(chunk) ----
    {
        float sr = sbuf[(sq * 2 + 0) * 128 + sn];
        float si = sbuf[(sq * 2 + 1) * 128 + sn];
        float cr = sr, cii = si;
        const int r0 = sq * 32;
        for (int tt = 0; tt < 32; ++tt) {
            float trr = Ar * cr - Ai * cii;
            cii = Ar * cii + Ai * cr;
            cr = trr;
            xbuf[(r0 + tt) * 260 + sn]       += cr;
            xbuf[(r0 + tt) * 260 + 128 + sn] += cii;
        }
    }
    __syncthreads();

    // ---- write x tile to global ----
    {
        const int orow = t >> 2, opart = t & 3;
        float* dst = xout + (size_t)(m0 + orow) * 256 + opart * 64;
        const float* src = &xbuf[orow * 260 + opart * 64];
#pragma unroll
        for (int v = 0; v < 16; ++v)
            *(f32x4*)(dst + v * 4) = *(const f32x4*)(src + v * 4);
    }
}

// GEMM2: y[32768][768] = x[32768][256](f32->bf16) @ Cw^T + D*u
// 128x128 tile, BK=32, 4 waves, raw barriers + 2-deep prefetch.
__global__ __launch_bounds__(256, 3)
void gemm2(const float* __restrict__ A,
           const unsigned short* __restrict__ W,
           float* __restrict__ Cout,
           const float* __restrict__ Dp, const float* __restrict__ Up) {
    constexpr int K = 256, KT = 8, Nc = kF;
    __shared__ __align__(16) short As0[128 * 40];
    __shared__ __align__(16) short As1[128 * 40];
    __shared__ __align__(16) short Ws0[128 * 40];
    __shared__ __align__(16) short Ws1[128 * 40];

    // XCD-bijective swizzle (nwg = 1536, %8 == 0); n-blocks innermost so the
    // 6 blocks sharing an x-panel stay adjacent (L2 reuse).
    const int gx = gridDim.x;
    const int nwg = gx * gridDim.y;
    const int orig = blockIdx.y * gx + blockIdx.x;
    const int cpx = nwg >> 3;
    const int sw = (orig & 7) * cpx + (orig >> 3);
    const int m0 = (sw / gx) * 128;
    const int n0 = (sw % gx) * 128;

    const int t = threadIdx.x;
    const int sr = t >> 1, sh = t & 1;

    const int wave = t >> 6, lane = t & 63;
    const int wr = wave >> 1, wc = wave & 1;
    const int lr = lane & 15, lg = lane >> 4;

    f32x4 acc[4][4] = {};

    f32x4 aA0, aA1, aA2, aA3, aB0, aB1, aB2, aB3;
    uint4v wA0, wA1, wB0, wB1;
    const float* aptr = A + (size_t)(m0 + sr) * K + sh * 16;
    const unsigned short* wptr = W + (size_t)(n0 + sr) * K + sh * 16;

#define G2_LOAD(SET, kt) do { \
    const float* p_ = aptr + (kt) * 32; \
    a##SET##0 = *(const f32x4*)p_;        a##SET##1 = *(const f32x4*)(p_ + 4); \
    a##SET##2 = *(const f32x4*)(p_ + 8);  a##SET##3 = *(const f32x4*)(p_ + 12); \
    const unsigned short* q_ = wptr + (kt) * 32; \
    w##SET##0 = *(const uint4v*)q_; w##SET##1 = *(const uint4v*)(q_ + 8); \
} while (0)

#define G2_WRITE(Asb, Wsb, a0, a1, a2, a3, w0, w1) do { \
    short h_[16]; \
    _Pragma("unroll") for (int e_ = 0; e_ < 4; ++e_) { \
        h_[e_]      = (short)f2bf(a0[e_]); \
        h_[4 + e_]  = (short)f2bf(a1[e_]); \
        h_[8 + e_]  = (short)f2bf(a2[e_]); \
        h_[12 + e_] = (short)f2bf(a3[e_]); \
    } \
    const int o_ = sr * 40 + sh * 16; \
    *(short8*)(&Asb[o_])     = *(short8*)&h_[0]; \
    *(short8*)(&Asb[o_ + 8]) = *(short8*)&h_[8]; \
    *(short8*)(&Wsb[o_])     = *(short8*)&w0; \
    *(short8*)(&Wsb[o_ + 8]) = *(short8*)&w1; \
} while (0)

#define G2_MMA(Asb, Wsb) do { \
    short8 ah_[4], bh_[4]; \
    _Pragma("unroll") for (int i_ = 0; i_ < 4; ++i_) { \
        ah_[i_] = *(const short8*)(&Asb[(wr * 64 + i_ * 16 + lr) * 40 + lg * 8]); \
        bh_[i_] = *(const short8*)(&Wsb[(wc * 64 + i_ * 16 + lr) * 40 + lg * 8]); \
    } \
    _Pragma("unroll") for (int i_ = 0; i_ < 4; ++i_) \
    _Pragma("unroll") for (int j_ = 0; j_ < 4; ++j_) \
        acc[i_][j_] = __builtin_amdgcn_mfma_f32_16x16x32_bf16(ah_[i_], bh_[j_], acc[i_][j_], 0, 0, 0); \
} while (0)

    G2_LOAD(A, 0);
    G2_LOAD(B, 1);
    for (int kt = 0; kt < KT; kt += 2) {
        G2_WRITE(As0, Ws0, aA0, aA1, aA2, aA3, wA0, wA1);
        if (kt + 2 < KT) G2_LOAD(A, kt + 2);
        LGKM0_BAR();
        G2_MMA(As0, Ws0);
        G2_WRITE(As1, Ws1, aB0, aB1, aB2, aB3, wB0, wB1);
        if (kt + 3 < KT) G2_LOAD(B, kt + 3);
        LGKM0_BAR();
        G2_MMA(As1, Ws1);
    }

    // epilogue: C/D layout col=lane&15, row=(lane>>4)*4+reg
#pragma unroll
    for (int i = 0; i < 4; ++i)
#pragma unroll
        for (int j = 0; j < 4; ++j) {
            const int col = n0 + wc * 64 + j * 16 + lr;
#pragma unroll
            for (int q = 0; q < 4; ++q) {
                const int row = m0 + wr * 64 + i * 16 + lg * 4 + q;
                float v = acc[i][j][q];
                v = fmaf(Dp[col], Up[(size_t)row * Nc + col], v);
                Cout[(size_t)row * Nc + col] = v;
            }
        }
}

extern "C" void kernel_launch(void* const* d_in, const int* in_sizes, int n_in,
                              void* d_out, int out_size, void* d_ws, size_t ws_size,
                              hipStream_t stream) {
    const float* u          = (const float*)d_in[0];
    const float* log_A_real = (const float*)d_in[1];
    const float* A_imag     = (const float*)d_in[2];
    const float* B_re       = (const float*)d_in[3];
    const float* B_im       = (const float*)d_in[4];
    const float* C_re       = (const float*)d_in[5];
    const float* C_im       = (const float*)d_in[6];
    const float* D          = (const float*)d_in[7];
    const float* log_dt     = (const float*)d_in[8];

    char* wsb = (char*)d_ws;
    float* wsf            = (float*)wsb;
    unsigned short* bw    = (unsigned short*)(wsb + kOffBw);
    unsigned short* cw    = (unsigned short*)(wsb + kOffCw);
    float* finals         = (float*)(wsb + kOffFinals);
    unsigned int* flags   = (unsigned int*)(wsb + kOffFlags);
    float* x              = (float*)(wsb + kOffX);
    float* y              = (float*)d_out;

    hipMemsetAsync(flags, 0, 256 * sizeof(unsigned int), stream);

    pre1<<<1, 128, 0, stream>>>(log_A_real, A_imag, log_dt, wsf);
    pre2<<<(256 * kF) / 256, 256, 0, stream>>>(B_re, B_im, wsf, bw);
    pre3<<<(kF * 256) / 256, 256, 0, stream>>>(C_re, C_im, cw);

    gemm1_scan<<<kM / 128, 512, 0, stream>>>(u, bw, x, finals, flags, wsf);

    gemm2<<<dim3(kF / 128, kM / 128), 256, 0, stream>>>(x, cw, y, D, u);
}

// Round 6
// 102.243 us; speedup vs baseline: 1.2649x; 1.2649x over previous
//
#include <hip/hip_runtime.h>
#include <hip/hip_bf16.h>
#include <math.h>

typedef __attribute__((ext_vector_type(8))) short short8;
typedef __attribute__((ext_vector_type(4))) float f32x4;
typedef __attribute__((ext_vector_type(4))) unsigned int uint4v;

// Problem constants (B=8, S=4096, F=768, N=128)
constexpr int kF = 768;
constexpr int kN = 128;
constexpr int kB = 8;
constexpr int kS = 4096;
constexpr int kM = kB * kS;          // 32768 rows
constexpr int kChunks = 128;         // scan chunks along S (per batch)
constexpr int kClen = 32;

// Workspace layout (BYTE offsets), ~18.1 MB total.
// Bu [32768][256] f32 lives in d_out (y overwrites it later; Bu dead by then).
// [0, 4096)           scalars f32: [0]Ar [128]Ai [256]P1r(A^32) [384]P1i
//                     [512]coef_r [640]coef_i
// [4096, +393216)     Bw [256][768] bf16 : row c (c<128 Re, else Im of coef*B)
// [397312, +393216)   Cw [768][256] bf16 : row f, k<128 = C_re[f][k], else -C_im
// [790528, +262144)   finals  [8*128 chunks][256] f32
// [1052672, +262144)  carries [8*128][256] f32
// [1314816, +16777216) x_bf16 [32768][256] ushort
constexpr size_t kOffBw      = 4096;
constexpr size_t kOffCw      = 397312;
constexpr size_t kOffFinals  = 790528;
constexpr size_t kOffCarries = 1052672;
constexpr size_t kOffXbf     = 1314816;

// Software round-to-nearest-even f32->bf16. Round 5 regressed to absmax=0.35
// using __float2bfloat16 here (truncation-biased); f2bf is the proven-RNE path
// (absmax=0.0625 in rounds 2-4). Do not swap back without an A/B.
__device__ __forceinline__ unsigned short f2bf(float f) {
    unsigned int u = __builtin_bit_cast(unsigned int, f);
    u += 0x7fffu + ((u >> 16) & 1u);   // round-to-nearest-even
    return (unsigned short)(u >> 16);
}

#define LGKM0_BAR() do { \
    asm volatile("s_waitcnt lgkmcnt(0)" ::: "memory"); \
    __builtin_amdgcn_s_barrier(); \
    __builtin_amdgcn_sched_barrier(0); \
} while (0)

__global__ __launch_bounds__(128)
void pre1(const float* __restrict__ log_A_real, const float* __restrict__ A_imag,
          const float* __restrict__ log_dt, float* __restrict__ ws) {
    int n = threadIdx.x;
    float dt = expf(log_dt[n]);
    float ar = -expf(log_A_real[n]);
    float ai = A_imag[n];
    float er = expf(ar * dt);
    float Ar = er * cosf(ai * dt);
    float Ai = er * sinf(ai * dt);
    // coef = (A_bar - 1) / (A_diag + 1e-8)
    float dr = ar + 1e-8f, di = ai;
    float inv = 1.0f / (dr * dr + di * di);
    float nr = Ar - 1.0f, ni = Ai;
    float cr = (nr * dr + ni * di) * inv;
    float ci = (ni * dr - nr * di) * inv;
    // P1 = A^32 by repeated multiply (matches scan semantics)
    float pr = 1.f, pi = 0.f;
    for (int i = 0; i < kClen; ++i) {
        float t = pr * Ar - pi * Ai;
        pi = pr * Ai + pi * Ar;
        pr = t;
    }
    ws[n] = Ar;        ws[128 + n] = Ai;
    ws[256 + n] = pr;  ws[384 + n] = pi;
    ws[512 + n] = cr;  ws[640 + n] = ci;
}

__global__ __launch_bounds__(256)
void pre2(const float* __restrict__ B_re, const float* __restrict__ B_im,
          const float* __restrict__ wsf, unsigned short* __restrict__ bw) {
    int id = blockIdx.x * 256 + threadIdx.x;   // 0 .. 256*768-1
    int c = id / kF;
    int f = id - c * kF;
    int n = c & 127;
    float cr = wsf[512 + n], ci = wsf[640 + n];
    float br = B_re[n * kF + f], bi = B_im[n * kF + f];
    float v = (c < 128) ? (cr * br - ci * bi) : (cr * bi + ci * br);
    bw[id] = f2bf(v);
}

__global__ __launch_bounds__(256)
void pre3(const float* __restrict__ C_re, const float* __restrict__ C_im,
          unsigned short* __restrict__ cw) {
    int id = blockIdx.x * 256 + threadIdx.x;   // 0 .. 768*256-1
    int f = id >> 8;
    int k = id & 255;
    float v = (k < 128) ? C_re[f * kN + k] : -C_im[f * kN + (k - 128)];
    cw[id] = f2bf(v);
}

// GEMM1: Bu[32768][256] = u[32768][768](f32->bf16 RNE) @ Bw^T (Bw [256][768] bf16)
// 128x128 tile, BK=32, 4 waves, raw barriers (lgkm-only) + 2-deep prefetch.
__global__ __launch_bounds__(256, 2)
void gemm1(const float* __restrict__ A,
           const unsigned short* __restrict__ W,
           float* __restrict__ Cout) {
    constexpr int K = kF, KT = K / 32;   // 24
    __shared__ __align__(16) short As0[128 * 40];
    __shared__ __align__(16) short As1[128 * 40];
    __shared__ __align__(16) short Ws0[128 * 40];
    __shared__ __align__(16) short Ws1[128 * 40];

    // XCD-bijective swizzle (nwg = 512, %8 == 0)
    const int gx = gridDim.x;
    const int nwg = gx * gridDim.y;
    const int orig = blockIdx.y * gx + blockIdx.x;
    const int cpx = nwg >> 3;
    const int sw = (orig & 7) * cpx + (orig >> 3);
    const int m0 = (sw / gx) * 128;
    const int n0 = (sw % gx) * 128;

    const int t = threadIdx.x;
    const int sr = t >> 1, sh = t & 1;

    const int wave = t >> 6, lane = t & 63;
    const int wr = wave >> 1, wc = wave & 1;
    const int lr = lane & 15, lg = lane >> 4;

    f32x4 acc[4][4] = {};

    f32x4 aA0, aA1, aA2, aA3, aB0, aB1, aB2, aB3;
    uint4v wA0, wA1, wB0, wB1;
    const float* aptr = A + (size_t)(m0 + sr) * K + sh * 16;
    const unsigned short* wptr = W + (size_t)(n0 + sr) * K + sh * 16;

#define G1_LOAD(SET, kt) do { \
    const float* p_ = aptr + (kt) * 32; \
    a##SET##0 = *(const f32x4*)p_;        a##SET##1 = *(const f32x4*)(p_ + 4); \
    a##SET##2 = *(const f32x4*)(p_ + 8);  a##SET##3 = *(const f32x4*)(p_ + 12); \
    const unsigned short* q_ = wptr + (kt) * 32; \
    w##SET##0 = *(const uint4v*)q_; w##SET##1 = *(const uint4v*)(q_ + 8); \
} while (0)

#define G1_WRITE(Asb, Wsb, a0, a1, a2, a3, w0, w1) do { \
    short h_[16]; \
    _Pragma("unroll") for (int e_ = 0; e_ < 4; ++e_) { \
        h_[e_]      = (short)f2bf(a0[e_]); \
        h_[4 + e_]  = (short)f2bf(a1[e_]); \
        h_[8 + e_]  = (short)f2bf(a2[e_]); \
        h_[12 + e_] = (short)f2bf(a3[e_]); \
    } \
    const int o_ = sr * 40 + sh * 16; \
    *(short8*)(&Asb[o_])     = *(short8*)&h_[0]; \
    *(short8*)(&Asb[o_ + 8]) = *(short8*)&h_[8]; \
    *(short8*)(&Wsb[o_])     = *(short8*)&w0; \
    *(short8*)(&Wsb[o_ + 8]) = *(short8*)&w1; \
} while (0)

#define G1_MMA(Asb, Wsb) do { \
    short8 ah_[4], bh_[4]; \
    _Pragma("unroll") for (int i_ = 0; i_ < 4; ++i_) { \
        ah_[i_] = *(const short8*)(&Asb[(wr * 64 + i_ * 16 + lr) * 40 + lg * 8]); \
        bh_[i_] = *(const short8*)(&Wsb[(wc * 64 + i_ * 16 + lr) * 40 + lg * 8]); \
    } \
    _Pragma("unroll") for (int i_ = 0; i_ < 4; ++i_) \
    _Pragma("unroll") for (int j_ = 0; j_ < 4; ++j_) \
        acc[i_][j_] = __builtin_amdgcn_mfma_f32_16x16x32_bf16(ah_[i_], bh_[j_], acc[i_][j_], 0, 0, 0); \
} while (0)

    G1_LOAD(A, 0);
    G1_LOAD(B, 1);
    for (int kt = 0; kt < KT; kt += 2) {
        G1_WRITE(As0, Ws0, aA0, aA1, aA2, aA3, wA0, wA1);
        if (kt + 2 < KT) G1_LOAD(A, kt + 2);
        LGKM0_BAR();
        G1_MMA(As0, Ws0);
        G1_WRITE(As1, Ws1, aB0, aB1, aB2, aB3, wB0, wB1);
        if (kt + 3 < KT) G1_LOAD(B, kt + 3);
        LGKM0_BAR();
        G1_MMA(As1, Ws1);
    }

    // epilogue: C/D layout col=lane&15, row=(lane>>4)*4+reg [m89-verified]
#pragma unroll
    for (int i = 0; i < 4; ++i)
#pragma unroll
        for (int j = 0; j < 4; ++j) {
            const int col = n0 + wc * 64 + j * 16 + lr;
#pragma unroll
            for (int q = 0; q < 4; ++q) {
                const int row = m0 + wr * 64 + i * 16 + lg * 4 + q;
                Cout[(size_t)row * 256 + col] = acc[i][j][q];
            }
        }
#undef G1_LOAD
#undef G1_WRITE
#undef G1_MMA
}

// Phase A: per (b, chunk), local scan with zero init; save chunk-final state.
__global__ __launch_bounds__(128)
void scanA(const float* __restrict__ Bu, const float* __restrict__ wsc,
           float* __restrict__ finals) {
    int n = threadIdx.x;
    int blk = blockIdx.x;            // b*kChunks + c
    int b = blk >> 7, c = blk & 127;
    float Ar = wsc[n], Ai = wsc[128 + n];
    float xr = 0.f, xi = 0.f;
    size_t base = ((size_t)(b * kS + c * kClen)) * 256;
#pragma unroll 8
    for (int s = 0; s < kClen; ++s) {
        float br = Bu[base + n], bi = Bu[base + 128 + n];
        float tr = Ar * xr - Ai * xi + br;
        xi = Ar * xi + Ai * xr + bi;
        xr = tr;
        base += 256;
    }
    finals[(size_t)blk * 256 + n] = xr;
    finals[(size_t)blk * 256 + 128 + n] = xi;
}

// Phase B: serial scan over chunk finals -> exclusive carries.
__global__ __launch_bounds__(128)
void scanB(const float* __restrict__ finals, const float* __restrict__ ws,
           float* __restrict__ carries) {
    int n = threadIdx.x;
    int b = blockIdx.x;
    float Pr = ws[256 + n], Pi = ws[384 + n];
    float xr = 0.f, xi = 0.f;
#pragma unroll 8
    for (int c = 0; c < kChunks; ++c) {
        size_t o = ((size_t)(b * kChunks + c)) * 256;
        carries[o + n] = xr;
        carries[o + 128 + n] = xi;
        float fr = finals[o + n], fi = finals[o + 128 + n];
        float tr = Pr * xr - Pi * xi + fr;
        xi = Pr * xi + Pi * xr + fi;
        xr = tr;
    }
}

// Phase C: redo local scan seeded with carry; emit x as bf16 RNE (GEMM2 input).
__global__ __launch_bounds__(128)
void scanC(const float* __restrict__ Bu, const float* __restrict__ wsc,
           const float* __restrict__ carries, unsigned short* __restrict__ xbf) {
    int n = threadIdx.x;
    int blk = blockIdx.x;
    int b = blk >> 7, c = blk & 127;
    float Ar = wsc[n], Ai = wsc[128 + n];
    size_t co = (size_t)blk * 256;
    float xr = carries[co + n], xi = carries[co + 128 + n];
    size_t base = ((size_t)(b * kS + c * kClen)) * 256;
#pragma unroll 4
    for (int s = 0; s < kClen; ++s) {
        float br = Bu[base + n], bi = Bu[base + 128 + n];
        float tr = Ar * xr - Ai * xi + br;
        xi = Ar * xi + Ai * xr + bi;
        xr = tr;
        xbf[base + n]       = f2bf(xr);
        xbf[base + 128 + n] = f2bf(xi);
        base += 256;
    }
}

// GEMM2: y[32768][768] = x_bf16[32768][256] @ Cw^T + D*u
// 128x128 tile, BK=32, 4 waves, raw barriers + 2-deep prefetch, zero convert.
__global__ __launch_bounds__(256, 3)
void gemm2(const unsigned short* __restrict__ A,
           const unsigned short* __restrict__ W,
           float* __restrict__ Cout,
           const float* __restrict__ Dp, const float* __restrict__ Up) {
    constexpr int K = 256, KT = 8, Nc = kF;
    __shared__ __align__(16) short As0[128 * 40];
    __shared__ __align__(16) short As1[128 * 40];
    __shared__ __align__(16) short Ws0[128 * 40];
    __shared__ __align__(16) short Ws1[128 * 40];

    // XCD-bijective swizzle (nwg = 1536, %8 == 0); n-blocks innermost.
    const int gx = gridDim.x;
    const int nwg = gx * gridDim.y;
    const int orig = blockIdx.y * gx + blockIdx.x;
    const int cpx = nwg >> 3;
    const int sw = (orig & 7) * cpx + (orig >> 3);
    const int m0 = (sw / gx) * 128;
    const int n0 = (sw % gx) * 128;

    const int t = threadIdx.x;
    const int sr = t >> 1, sh = t & 1;

    const int wave = t >> 6, lane = t & 63;
    const int wr = wave >> 1, wc = wave & 1;
    const int lr = lane & 15, lg = lane >> 4;

    f32x4 acc[4][4] = {};

    uint4v aA0, aA1, aB0, aB1;
    uint4v wA0, wA1, wB0, wB1;
    const unsigned short* aptr = A + (size_t)(m0 + sr) * K + sh * 16;
    const unsigned short* wptr = W + (size_t)(n0 + sr) * K + sh * 16;

#define G2_LOAD(SET, kt) do { \
    const unsigned short* p_ = aptr + (kt) * 32; \
    a##SET##0 = *(const uint4v*)p_; a##SET##1 = *(const uint4v*)(p_ + 8); \
    const unsigned short* q_ = wptr + (kt) * 32; \
    w##SET##0 = *(const uint4v*)q_; w##SET##1 = *(const uint4v*)(q_ + 8); \
} while (0)

#define G2_WRITE(Asb, Wsb, a0, a1, w0, w1) do { \
    const int o_ = sr * 40 + sh * 16; \
    *(short8*)(&Asb[o_])     = *(short8*)&a0; \
    *(short8*)(&Asb[o_ + 8]) = *(short8*)&a1; \
    *(short8*)(&Wsb[o_])     = *(short8*)&w0; \
    *(short8*)(&Wsb[o_ + 8]) = *(short8*)&w1; \
} while (0)

#define G2_MMA(Asb, Wsb) do { \
    short8 ah_[4], bh_[4]; \
    _Pragma("unroll") for (int i_ = 0; i_ < 4; ++i_) { \
        ah_[i_] = *(const short8*)(&Asb[(wr * 64 + i_ * 16 + lr) * 40 + lg * 8]); \
        bh_[i_] = *(const short8*)(&Wsb[(wc * 64 + i_ * 16 + lr) * 40 + lg * 8]); \
    } \
    _Pragma("unroll") for (int i_ = 0; i_ < 4; ++i_) \
    _Pragma("unroll") for (int j_ = 0; j_ < 4; ++j_) \
        acc[i_][j_] = __builtin_amdgcn_mfma_f32_16x16x32_bf16(ah_[i_], bh_[j_], acc[i_][j_], 0, 0, 0); \
} while (0)

    G2_LOAD(A, 0);
    G2_LOAD(B, 1);
    for (int kt = 0; kt < KT; kt += 2) {
        G2_WRITE(As0, Ws0, aA0, aA1, wA0, wA1);
        if (kt + 2 < KT) G2_LOAD(A, kt + 2);
        LGKM0_BAR();
        G2_MMA(As0, Ws0);
        G2_WRITE(As1, Ws1, aB0, aB1, wB0, wB1);
        if (kt + 3 < KT) G2_LOAD(B, kt + 3);
        LGKM0_BAR();
        G2_MMA(As1, Ws1);
    }

    // epilogue: C/D layout col=lane&15, row=(lane>>4)*4+reg
#pragma unroll
    for (int i = 0; i < 4; ++i)
#pragma unroll
        for (int j = 0; j < 4; ++j) {
            const int col = n0 + wc * 64 + j * 16 + lr;
#pragma unroll
            for (int q = 0; q < 4; ++q) {
                const int row = m0 + wr * 64 + i * 16 + lg * 4 + q;
                float v = acc[i][j][q];
                v = fmaf(Dp[col], Up[(size_t)row * Nc + col], v);
                Cout[(size_t)row * Nc + col] = v;
            }
        }
#undef G2_LOAD
#undef G2_WRITE
#undef G2_MMA
}

extern "C" void kernel_launch(void* const* d_in, const int* in_sizes, int n_in,
                              void* d_out, int out_size, void* d_ws, size_t ws_size,
                              hipStream_t stream) {
    const float* u          = (const float*)d_in[0];
    const float* log_A_real = (const float*)d_in[1];
    const float* A_imag     = (const float*)d_in[2];
    const float* B_re       = (const float*)d_in[3];
    const float* B_im       = (const float*)d_in[4];
    const float* C_re       = (const float*)d_in[5];
    const float* C_im       = (const float*)d_in[6];
    const float* D          = (const float*)d_in[7];
    const float* log_dt     = (const float*)d_in[8];

    char* wsb = (char*)d_ws;
    float* wsf            = (float*)wsb;
    unsigned short* bw    = (unsigned short*)(wsb + kOffBw);
    unsigned short* cw    = (unsigned short*)(wsb + kOffCw);
    float* finals         = (float*)(wsb + kOffFinals);
    float* carries        = (float*)(wsb + kOffCarries);
    unsigned short* xbf   = (unsigned short*)(wsb + kOffXbf);
    float* y              = (float*)d_out;
    // Bu (f32 [32768][256], 33.5 MB) lives in d_out; it is fully dead before
    // gemm2 overwrites d_out with y (gemm2 reads only xbf/u/weights).
    float* Bu             = (float*)d_out;

    pre1<<<1, 128, 0, stream>>>(log_A_real, A_imag, log_dt, wsf);
    pre2<<<(256 * kF) / 256, 256, 0, stream>>>(B_re, B_im, wsf, bw);
    pre3<<<(kF * 256) / 256, 256, 0, stream>>>(C_re, C_im, cw);

    // Bu = u @ Bw^T
    gemm1<<<dim3(2, kM / 128), 256, 0, stream>>>(u, bw, Bu);

    scanA<<<kB * kChunks, 128, 0, stream>>>(Bu, wsf, finals);
    scanB<<<kB, 128, 0, stream>>>(finals, wsf, carries);
    scanC<<<kB * kChunks, 128, 0, stream>>>(Bu, wsf, carries, xbf);

    // y = x @ Cw^T + D*u
    gemm2<<<dim3(kF / 128, kM / 128), 256, 0, stream>>>(xbf, cw, y, D, u);
}